// Round 5
// baseline (1192.138 us; speedup 1.0000x reference)
//
#include <hip/hip_runtime.h>
#include <stdint.h>

#define TTOK 16384
#define NDIM 1024
#define NHID 2048
#define NEXP 8
#define TM 256
#define MAXT 136
#define SLOTCAP (2 * TTOK + NEXP * TM) /* 34816 */

typedef __attribute__((ext_vector_type(8))) short short8;
typedef __attribute__((ext_vector_type(4))) float f32x4;

__device__ __forceinline__ unsigned short f2bf(float f) {
  unsigned int u = __float_as_uint(f);
  u += 0x7FFFu + ((u >> 16) & 1u);
  return (unsigned short)(u >> 16);
}

__device__ __forceinline__ void gload16(const void* g, void* l) {
  __builtin_amdgcn_global_load_lds(
      (const __attribute__((address_space(1))) unsigned int*)g,
      (__attribute__((address_space(3))) unsigned int*)l, 16, 0, 0);
}

__device__ __forceinline__ float silu(float z) {
  return z / (1.0f + __expf(-z));
}

// ---------------------------------------------------------------------------
// Router: one wave per token. f32 logits, softmax, top-2, renorm gates.
// ---------------------------------------------------------------------------
__global__ void k_router(const float* __restrict__ x, const float* __restrict__ rw,
                         unsigned short* __restrict__ xbf, int* __restrict__ tok_e,
                         float* __restrict__ tok_gw, unsigned int* __restrict__ counts) {
  int t = (blockIdx.x << 2) + (threadIdx.x >> 6);
  int lane = threadIdx.x & 63;
  const float4* xr = (const float4*)(x + (size_t)t * NDIM);

  float4 v[4];
  float d[NEXP];
#pragma unroll
  for (int e = 0; e < NEXP; ++e) d[e] = 0.f;

#pragma unroll
  for (int i = 0; i < 4; ++i) {
    int c = i * 64 + lane;
    v[i] = xr[c];
#pragma unroll
    for (int e = 0; e < NEXP; ++e) {
      float4 w = ((const float4*)(rw + e * NDIM))[c];
      d[e] += v[i].x * w.x + v[i].y * w.y + v[i].z * w.z + v[i].w * w.w;
    }
  }
#pragma unroll
  for (int e = 0; e < NEXP; ++e)
    for (int s = 32; s; s >>= 1) d[e] += __shfl_xor(d[e], s, 64);

  unsigned short* xo = xbf + (size_t)t * NDIM;
#pragma unroll
  for (int i = 0; i < 4; ++i) {
    int c = i * 64 + lane;
    ushort4 u;
    u.x = f2bf(v[i].x); u.y = f2bf(v[i].y); u.z = f2bf(v[i].z); u.w = f2bf(v[i].w);
    ((ushort4*)xo)[c] = u;
  }

  if (lane == 0) {
    float m = d[0];
#pragma unroll
    for (int e = 1; e < NEXP; ++e) m = fmaxf(m, d[e]);
    float ex[NEXP];
#pragma unroll
    for (int e = 0; e < NEXP; ++e) ex[e] = __expf(d[e] - m);
    int e0 = 0;
#pragma unroll
    for (int e = 1; e < NEXP; ++e) if (ex[e] > ex[e0]) e0 = e;
    int e1 = (e0 == 0) ? 1 : 0;
#pragma unroll
    for (int e = 0; e < NEXP; ++e) if (e != e0 && ex[e] > ex[e1]) e1 = e;
    float p0 = ex[e0], p1 = ex[e1];
    float inv = 1.f / (p0 + p1);
    tok_e[2 * t] = e0; tok_e[2 * t + 1] = e1;
    tok_gw[2 * t] = p0 * inv; tok_gw[2 * t + 1] = p1 * inv;
    atomicAdd(&counts[e0], 1u);
    atomicAdd(&counts[e1], 1u);
  }
}

// ---------------------------------------------------------------------------
// Offsets + tile table, 64 threads (redundant compute, parallel writes).
// ---------------------------------------------------------------------------
__global__ void k_offsets(const unsigned int* __restrict__ counts,
                          unsigned int* __restrict__ slotbase, unsigned int* __restrict__ cnt2,
                          unsigned int* __restrict__ tile_e, unsigned int* __restrict__ tile_m0) {
  int l = threadIdx.x;
  unsigned int c[NEXP], base[NEXP], tb[NEXP];
  unsigned int b = 0, t = 0;
#pragma unroll
  for (int e = 0; e < NEXP; ++e) {
    c[e] = counts[e];
    base[e] = b; tb[e] = t;
    unsigned int nt = (c[e] + TM - 1) / TM;
    b += nt * TM; t += nt;
  }
  if (l < NEXP) { slotbase[l] = base[l]; cnt2[l] = 0u; }
  for (int idx = l; idx < MAXT; idx += 64) {
    unsigned int te = 0xFFFFFFFFu, tm = 0;
#pragma unroll
    for (int e = 0; e < NEXP; ++e) {
      unsigned int nt = (c[e] + TM - 1) / TM;
      if ((unsigned)idx >= tb[e] && (unsigned)idx < tb[e] + nt) {
        te = (unsigned)e; tm = base[e] + ((unsigned)idx - tb[e]) * TM;
      }
    }
    tile_e[idx] = te; tile_m0[idx] = tm;
  }
}

// ---------------------------------------------------------------------------
// Fill: hierarchical LDS histogram; 8 global atomics per block.
// ---------------------------------------------------------------------------
__global__ void k_fill(const int* __restrict__ tok_e, const float* __restrict__ tok_gw,
                       const unsigned int* __restrict__ slotbase, unsigned int* __restrict__ cnt2,
                       unsigned int* __restrict__ tok_list, float* __restrict__ gate_list) {
  __shared__ unsigned int hcnt[NEXP];
  __shared__ unsigned int hbase[NEXP];
  int tid = threadIdx.x;
  int t = blockIdx.x * 256 + tid;
  if (tid < NEXP) hcnt[tid] = 0u;
  __syncthreads();
  int e0 = tok_e[2 * t], e1 = tok_e[2 * t + 1];
  float g0 = tok_gw[2 * t], g1 = tok_gw[2 * t + 1];
  unsigned int p0 = atomicAdd(&hcnt[e0], 1u);
  unsigned int p1 = atomicAdd(&hcnt[e1], 1u);
  __syncthreads();
  if (tid < NEXP) hbase[tid] = atomicAdd(&cnt2[tid], hcnt[tid]);
  __syncthreads();
  unsigned int s0 = slotbase[e0] + hbase[e0] + p0;
  unsigned int s1 = slotbase[e1] + hbase[e1] + p1;
  tok_list[s0] = (unsigned)t; gate_list[s0] = g0;
  tok_list[s1] = (unsigned)t; gate_list[s1] = g1;
}

// ---------------------------------------------------------------------------
// Transpose + f32->bf16 convert: src [b][R][C] f32 -> dst [b][C][R] bf16
// ---------------------------------------------------------------------------
__global__ void k_tconv(const float* __restrict__ src, unsigned short* __restrict__ dst,
                        int R, int C) {
  int b = blockIdx.z;
  src += (size_t)b * R * C;
  dst += (size_t)b * R * C;
  __shared__ unsigned short tile[64][65];
  int bx = blockIdx.x * 64, by = blockIdx.y * 64;
  int tx = threadIdx.x & 15, ty = threadIdx.x >> 4;
#pragma unroll
  for (int rr = 0; rr < 4; ++rr) {
    int rl = rr * 16 + ty;
    float4 v = *(const float4*)(src + (size_t)(by + rl) * C + bx + tx * 4);
    tile[rl][tx * 4 + 0] = f2bf(v.x);
    tile[rl][tx * 4 + 1] = f2bf(v.y);
    tile[rl][tx * 4 + 2] = f2bf(v.z);
    tile[rl][tx * 4 + 3] = f2bf(v.w);
  }
  __syncthreads();
#pragma unroll
  for (int rr = 0; rr < 4; ++rr) {
    int cl = rr * 16 + ty;
    ushort4 u;
    u.x = tile[tx * 4 + 0][cl];
    u.y = tile[tx * 4 + 1][cl];
    u.z = tile[tx * 4 + 2][cl];
    u.w = tile[tx * 4 + 3][cl];
    *(ushort4*)(dst + (size_t)(bx + cl) * R + by + tx * 4) = u;
  }
}

__global__ void k_sentinel(float* __restrict__ out, float v) {
  if (threadIdx.x == 0 && blockIdx.x == 0) out[0] = v;
}

// ---------------------------------------------------------------------------
// GEMM12: ring-3 counted-vmcnt (T3/T4) + T2 swizzle + T5 setprio.
// BM=128 (tile halves), BN=128 dual-B (W1,W2), BK=64, 8 waves 2Mx4N.
// LDS 144 KiB: 3 slots x (A 16K + B1 16K + B2 16K).
// 6 gload16/thread/K-tile -> vmcnt(12) steady, 6/0 tails.
// ---------------------------------------------------------------------------
__global__ __launch_bounds__(512, 2) void k_gemm12(
    const unsigned short* __restrict__ xbf, const unsigned short* __restrict__ w1t,
    const unsigned short* __restrict__ w2t, unsigned short* __restrict__ H,
    const unsigned int* __restrict__ tok_list, const unsigned int* __restrict__ tile_e,
    const unsigned int* __restrict__ tile_m0) {
  unsigned int e = tile_e[blockIdx.x >> 1];
  if (e > 7u) return;
  int m0 = (int)tile_m0[blockIdx.x >> 1] + (int)(blockIdx.x & 1) * 128;
  int n0 = blockIdx.y * 128;

  __shared__ unsigned short As[3][128 * 64];
  __shared__ unsigned short B1s[3][128 * 64];
  __shared__ unsigned short B2s[3][128 * 64];

  int tid = threadIdx.x, w = tid >> 6, l = tid & 63;
  int rsub = tid >> 3;                                // 0..63
  int swb = ((tid & 7) * 16) ^ ((rsub & 7) << 4);     // pre-swizzled byte col

  const unsigned short* aS[2];
  const unsigned short* b1S[2];
  const unsigned short* b2S[2];
#pragma unroll
  for (int j = 0; j < 2; ++j) {
    int row = j * 64 + rsub;
    aS[j] = xbf + (size_t)tok_list[m0 + row] * NDIM + (swb >> 1);
    size_t off = ((size_t)e * NHID + n0 + row) * NDIM + (swb >> 1);
    b1S[j] = w1t + off;
    b2S[j] = w2t + off;
  }
  int ldsb = w * 1024;  // wave-uniform byte base within a j-group

  f32x4 acc1[4][2], acc2[4][2];
#pragma unroll
  for (int m = 0; m < 4; ++m)
#pragma unroll
    for (int n = 0; n < 2; ++n) { acc1[m][n] = (f32x4)0.f; acc2[m][n] = (f32x4)0.f; }

  int wr = (w >> 2) * 64, wc = (w & 3) * 32;

  auto stage = [&](int kt, int s) {
    int ke = kt * 64;
    char* A = (char*)As + s * 16384;
    char* B1 = (char*)B1s + s * 16384;
    char* B2 = (char*)B2s + s * 16384;
#pragma unroll
    for (int j = 0; j < 2; ++j) {
      gload16(aS[j] + ke, A + j * 8192 + ldsb);
      gload16(b1S[j] + ke, B1 + j * 8192 + ldsb);
      gload16(b2S[j] + ke, B2 + j * 8192 + ldsb);
    }
  };

  auto compute = [&](int s) {
    const char* A = (const char*)As + s * 16384;
    const char* B1 = (const char*)B1s + s * 16384;
    const char* B2 = (const char*)B2s + s * 16384;
#pragma unroll
    for (int ks = 0; ks < 2; ++ks) {
      int kb = ks * 64 + ((l >> 4) << 4);
      short8 a[4], b1[2], b2[2];
#pragma unroll
      for (int m = 0; m < 4; ++m) {
        int r = wr + m * 16 + (l & 15);
        a[m] = *(const short8*)(A + r * 128 + (kb ^ ((r & 7) << 4)));
      }
#pragma unroll
      for (int n = 0; n < 2; ++n) {
        int r = wc + n * 16 + (l & 15);
        int o = r * 128 + (kb ^ ((r & 7) << 4));
        b1[n] = *(const short8*)(B1 + o);
        b2[n] = *(const short8*)(B2 + o);
      }
      __builtin_amdgcn_s_setprio(1);
#pragma unroll
      for (int m = 0; m < 4; ++m)
#pragma unroll
        for (int n = 0; n < 2; ++n) {
          acc1[m][n] = __builtin_amdgcn_mfma_f32_16x16x32_bf16(a[m], b1[n], acc1[m][n], 0, 0, 0);
          acc2[m][n] = __builtin_amdgcn_mfma_f32_16x16x32_bf16(a[m], b2[n], acc2[m][n], 0, 0, 0);
        }
      __builtin_amdgcn_s_setprio(0);
    }
  };

  stage(0, 0);
  stage(1, 1);
  for (int t = 0; t < 14; ++t) {
    stage(t + 2, (t + 2) % 3);
    asm volatile("s_waitcnt vmcnt(12)" ::: "memory");
    __builtin_amdgcn_s_barrier();
    compute(t % 3);
    __builtin_amdgcn_s_barrier();
  }
  asm volatile("s_waitcnt vmcnt(6)" ::: "memory");
  __builtin_amdgcn_s_barrier();
  compute(2);  // t = 14
  __builtin_amdgcn_s_barrier();
  asm volatile("s_waitcnt vmcnt(0)" ::: "memory");
  __builtin_amdgcn_s_barrier();
  compute(0);  // t = 15

#pragma unroll
  for (int m = 0; m < 4; ++m)
#pragma unroll
    for (int n = 0; n < 2; ++n) {
      int col = n0 + wc + n * 16 + (l & 15);
#pragma unroll
      for (int q = 0; q < 4; ++q) {
        int slot = m0 + wr + m * 16 + ((l >> 4) << 2) + q;
        float hv = silu(acc1[m][n][q]) * acc2[m][n][q];
        H[(size_t)slot * NHID + col] = f2bf(hv);
      }
    }
}

// ---------------------------------------------------------------------------
// GEMM3: same ring-3 skeleton. BM=128 (tile halves), BN=256, BK=64, K=2048.
// LDS 144 KiB: 3 slots x (A 16K + B 32K). 6 loads/thread/K-tile.
// Gated atomicAdd epilogue (2 real contributions/element -> deterministic).
// ---------------------------------------------------------------------------
__global__ __launch_bounds__(512, 2) void k_gemm3(
    const unsigned short* __restrict__ H, const unsigned short* __restrict__ w3t,
    float* __restrict__ out, const unsigned int* __restrict__ tok_list,
    const float* __restrict__ gate_list, const unsigned int* __restrict__ tile_e,
    const unsigned int* __restrict__ tile_m0) {
  unsigned int e = tile_e[blockIdx.x >> 1];
  if (e > 7u) return;
  int m0 = (int)tile_m0[blockIdx.x >> 1] + (int)(blockIdx.x & 1) * 128;
  int n0 = blockIdx.y * 256;

  __shared__ unsigned short As[3][128 * 64];
  __shared__ unsigned short Bs[3][256 * 64];

  int tid = threadIdx.x, w = tid >> 6, l = tid & 63;
  int rsub = tid >> 3;
  int swb = ((tid & 7) * 16) ^ ((rsub & 7) << 4);

  const unsigned short* aS[2];
  const unsigned short* bS[4];
#pragma unroll
  for (int j = 0; j < 2; ++j) {
    int row = j * 64 + rsub;
    aS[j] = H + (size_t)(m0 + row) * NHID + (swb >> 1);
  }
#pragma unroll
  for (int j = 0; j < 4; ++j) {
    int row = j * 64 + rsub;
    bS[j] = w3t + ((size_t)e * NDIM + n0 + row) * NHID + (swb >> 1);
  }
  int ldsb = w * 1024;

  f32x4 acc[4][4];
#pragma unroll
  for (int m = 0; m < 4; ++m)
#pragma unroll
    for (int n = 0; n < 4; ++n) acc[m][n] = (f32x4)0.f;

  int wr = (w >> 2) * 64, wc = (w & 3) * 64;

  auto stage = [&](int kt, int s) {
    int ke = kt * 64;
    char* A = (char*)As + s * 16384;
    char* B = (char*)Bs + s * 32768;
#pragma unroll
    for (int j = 0; j < 2; ++j)
      gload16(aS[j] + ke, A + j * 8192 + ldsb);
#pragma unroll
    for (int j = 0; j < 4; ++j)
      gload16(bS[j] + ke, B + j * 8192 + ldsb);
  };

  auto compute = [&](int s) {
    const char* A = (const char*)As + s * 16384;
    const char* B = (const char*)Bs + s * 32768;
#pragma unroll
    for (int ks = 0; ks < 2; ++ks) {
      int kb = ks * 64 + ((l >> 4) << 4);
      short8 a[4], b[4];
#pragma unroll
      for (int m = 0; m < 4; ++m) {
        int r = wr + m * 16 + (l & 15);
        a[m] = *(const short8*)(A + r * 128 + (kb ^ ((r & 7) << 4)));
      }
#pragma unroll
      for (int n = 0; n < 4; ++n) {
        int r = wc + n * 16 + (l & 15);
        b[n] = *(const short8*)(B + r * 128 + (kb ^ ((r & 7) << 4)));
      }
      __builtin_amdgcn_s_setprio(1);
#pragma unroll
      for (int m = 0; m < 4; ++m)
#pragma unroll
        for (int n = 0; n < 4; ++n)
          acc[m][n] = __builtin_amdgcn_mfma_f32_16x16x32_bf16(a[m], b[n], acc[m][n], 0, 0, 0);
      __builtin_amdgcn_s_setprio(0);
    }
  };

  stage(0, 0);
  stage(1, 1);
  for (int t = 0; t < 30; ++t) {
    stage(t + 2, (t + 2) % 3);
    asm volatile("s_waitcnt vmcnt(12)" ::: "memory");
    __builtin_amdgcn_s_barrier();
    compute(t % 3);
    __builtin_amdgcn_s_barrier();
  }
  asm volatile("s_waitcnt vmcnt(6)" ::: "memory");
  __builtin_amdgcn_s_barrier();
  compute(30 % 3);  // = 0
  __builtin_amdgcn_s_barrier();
  asm volatile("s_waitcnt vmcnt(0)" ::: "memory");
  __builtin_amdgcn_s_barrier();
  compute(31 % 3);  // = 1

#pragma unroll
  for (int m = 0; m < 4; ++m)
#pragma unroll
    for (int q = 0; q < 4; ++q) {
      int slot = m0 + wr + m * 16 + ((l >> 4) << 2) + q;
      unsigned int tok = tok_list[slot];
      float g = gate_list[slot];
      if (g != 0.f) {
        float* orow = out + (size_t)tok * NDIM + n0 + wc;
#pragma unroll
        for (int n = 0; n < 4; ++n)
          atomicAdd(orow + n * 16 + (l & 15), acc[m][n][q] * g);
      }
    }
}

// ---------------------------------------------------------------------------
extern "C" void kernel_launch(void* const* d_in, const int* in_sizes, int n_in,
                              void* d_out, int out_size, void* d_ws, size_t ws_size,
                              hipStream_t stream) {
  const float* x = (const float*)d_in[0];
  const float* rw = (const float*)d_in[1];
  const float* w1 = (const float*)d_in[2];
  const float* w2 = (const float*)d_in[3];
  const float* w3 = (const float*)d_in[4];
  float* out = (float*)d_out;
  char* ws = (char*)d_ws;

  size_t o = 0;
  auto alloc = [&](size_t b) { size_t r = o; o = (o + b + 255) & ~(size_t)255; return r; };
  size_t o_xbf = alloc((size_t)TTOK * NDIM * 2);
  size_t o_w3t = alloc((size_t)NEXP * NDIM * NHID * 2);
  size_t o_H = alloc((size_t)SLOTCAP * NHID * 2);
  size_t o_tok = alloc((size_t)SLOTCAP * 4);
  size_t o_gate = alloc((size_t)SLOTCAP * 4);
  size_t o_te = alloc((size_t)TTOK * 2 * 4);
  size_t o_tg = alloc((size_t)TTOK * 2 * 4);
  size_t o_cnt = alloc(64);
  size_t o_cnt2 = alloc(64);
  size_t o_sb = alloc(64);
  size_t o_tle = alloc(MAXT * 4 + 64);
  size_t o_tlm = alloc(MAXT * 4 + 64);
  size_t need = o;

  size_t outBytes = (size_t)out_size * sizeof(float);
  size_t wtBytes = (size_t)NEXP * NDIM * NHID * 2;  // 32 MiB each

  if (ws_size < need || outBytes < 2 * wtBytes) {
    hipMemsetAsync(d_out, 0, outBytes, stream);
    k_sentinel<<<1, 64, 0, stream>>>(out, (float)((double)ws_size / 1048576.0));
    return;
  }

  unsigned short* xbf = (unsigned short*)(ws + o_xbf);
  unsigned short* w3t = (unsigned short*)(ws + o_w3t);
  unsigned short* Hbuf = (unsigned short*)(ws + o_H);
  unsigned int* tok_list = (unsigned int*)(ws + o_tok);
  float* gate_list = (float*)(ws + o_gate);
  int* tok_e = (int*)(ws + o_te);
  float* tok_gw = (float*)(ws + o_tg);
  unsigned int* counts = (unsigned int*)(ws + o_cnt);
  unsigned int* cnt2 = (unsigned int*)(ws + o_cnt2);
  unsigned int* slotbase = (unsigned int*)(ws + o_sb);
  unsigned int* tile_e = (unsigned int*)(ws + o_tle);
  unsigned int* tile_m0 = (unsigned int*)(ws + o_tlm);

  unsigned short* w1t = (unsigned short*)d_out;  // d_out as scratch pre-gemm3
  unsigned short* w2t = (unsigned short*)((char*)d_out + wtBytes);

  hipMemsetAsync(counts, 0, 64, stream);
  hipMemsetAsync(tok_list, 0, (size_t)SLOTCAP * 4, stream);
  hipMemsetAsync(gate_list, 0, (size_t)SLOTCAP * 4, stream);

  k_router<<<TTOK / 4, 256, 0, stream>>>(x, rw, xbf, tok_e, tok_gw, counts);
  k_offsets<<<1, 64, 0, stream>>>(counts, slotbase, cnt2, tile_e, tile_m0);
  k_fill<<<TTOK / 256, 256, 0, stream>>>(tok_e, tok_gw, slotbase, cnt2, tok_list, gate_list);

  k_tconv<<<dim3(NHID / 64, NDIM / 64, NEXP), 256, 0, stream>>>(w1, w1t, NDIM, NHID);
  k_tconv<<<dim3(NHID / 64, NDIM / 64, NEXP), 256, 0, stream>>>(w2, w2t, NDIM, NHID);
  k_tconv<<<dim3(NDIM / 64, NHID / 64, NEXP), 256, 0, stream>>>(w3, w3t, NHID, NDIM);

  k_gemm12<<<dim3(2 * MAXT, NHID / 128), 512, 0, stream>>>(xbf, w1t, w2t, Hbuf, tok_list,
                                                           tile_e, tile_m0);

  hipMemsetAsync(d_out, 0, outBytes, stream);

  k_gemm3<<<dim3(2 * MAXT, NDIM / 256), 512, 0, stream>>>(Hbuf, w3t, out, tok_list, gate_list,
                                                          tile_e, tile_m0);
}